// Round 3
// baseline (58.570 us; speedup 1.0000x reference)
//
#include <hip/hip_runtime.h>

// Problem constants (fixed by the reference).
constexpr int kN = 2048;
constexpr int kB = 16;
constexpr int kNB = 128;  // NUM_BUCKETS

// fl32(ln2) = 0x3F317218 — what any f32 log chain divides by (log(2.0f)).
#define LN2_BITS 0x3f317218u

// ---------------------------------------------------------------------------
// Kernel 1: rel_pos_bias[i][j] = pos_w[(N-1) + j - i]  (PASSED in R1/R2)
// ---------------------------------------------------------------------------
__global__ __launch_bounds__(256) void pos_kernel(const float* __restrict__ pos_w,
                                                  float* __restrict__ out) {
    __shared__ float lds[2 * kN - 1];
    const int i = blockIdx.x;
    for (int t = threadIdx.x; t < 2 * kN - 1; t += 256) lds[t] = pos_w[t];
    __syncthreads();
    const int base = kN - 1 - i;
    float* __restrict__ orow = out + (size_t)i * kN;
    #pragma unroll
    for (int k = 0; k < kN / 256; ++k) {
        const int j = k * 256 + threadIdx.x;
        orow[j] = lds[base + j];
    }
}

// ---------------------------------------------------------------------------
// Bucket matching the all-f32 arbiter chain with correctly-rounded f32 log:
//   bk = clip( floorf( fl32( CRlog32(a) / fl32(ln2) ) ), 0, 128 ), a = max(|dt|,1)
// Fast path 31-clz(a) is provably identical outside |a - 2^j| <= 2^j*j*1.22e-7
// (total relative error of the chain <= 2*2^-24 + 2e-9 per unit of q).
// Windows use ~2x that half-width. CR f32 log inside = (float)log((double)a)
// (f64 log err ~2e-16 << f32 half-ulp 3e-8 -> double rounding safe).
// ---------------------------------------------------------------------------
__device__ __forceinline__ int bucket_of(int rowts, int tj) {
    int dt = rowts - tj;
    unsigned a = (unsigned)(dt < 0 ? -dt : dt);
    a = a < 1u ? 1u : a;                   // a in [1, 10^7) < 2^24
    int k = 31 - __clz((int)a);            // exact floor(log2(a))
    unsigned p = 1u << k;
    // windows: lower side of 2^k, upper side approaching 2^(k+1)
    unsigned Wlo = ((p >> 20) * (unsigned)k) + 8u;
    unsigned Whi = ((p >> 19) * (unsigned)(k + 1)) + 8u;
    bool danger = ((a - p) < Wlo) | (((p << 1) - a) < Whi);
    if (!danger) return k;
    float L = (float)log((double)a);       // correctly-rounded f32 log(a)
    float q = L / __uint_as_float(LN2_BITS);  // IEEE f32 divide (no fast-math)
    int bk = (int)floorf(q);
    return bk < 0 ? 0 : (bk > kNB ? kNB : bk);
}

__global__ __launch_bounds__(256) void ts_kernel(const int* __restrict__ ts,
                                                 const float* __restrict__ ts_w,
                                                 float* __restrict__ out) {
    __shared__ float w[kNB + 1];
    if (threadIdx.x <= kNB) w[threadIdx.x] = ts_w[threadIdx.x];
    __syncthreads();

    const int bi = blockIdx.x;          // b * N + i
    const int b  = bi >> 11;            // / kN
    const int i  = bi & (kN - 1);

    const int* __restrict__ tsrow = ts + (size_t)b * kN;
    const int rowts = tsrow[min(i + 1, kN - 1)];

    const int4* __restrict__ ts4 = (const int4*)tsrow;
    float4* __restrict__ orow4 =
        (float4*)(out + (size_t)kN * kN + (size_t)bi * kN);

    #pragma unroll
    for (int kk = 0; kk < kN / (4 * 256); ++kk) {
        const int v = kk * 256 + threadIdx.x;
        const int4 t4 = ts4[v];
        float4 r;
        r.x = w[bucket_of(rowts, t4.x)];
        r.y = w[bucket_of(rowts, t4.y)];
        r.z = w[bucket_of(rowts, t4.z)];
        r.w = w[bucket_of(rowts, t4.w)];
        orow4[v] = r;
    }
}

extern "C" void kernel_launch(void* const* d_in, const int* in_sizes, int n_in,
                              void* d_out, int out_size, void* d_ws, size_t ws_size,
                              hipStream_t stream) {
    const int*   all_ts = (const int*)d_in[0];    // (B, N) int32
    const float* pos_w  = (const float*)d_in[1];  // (2N-1,) f32
    const float* ts_w   = (const float*)d_in[2];  // (NB+1,) f32
    float* out = (float*)d_out;                   // [N*N] pos ++ [B*N*N] ts

    pos_kernel<<<kN, 256, 0, stream>>>(pos_w, out);
    ts_kernel<<<kB * kN, 256, 0, stream>>>(all_ts, ts_w, out);
}

// Round 5
// 50.065 us; speedup vs baseline: 1.1699x; 1.1699x over previous
//
#include <hip/hip_runtime.h>

// Problem constants (fixed by the reference).
constexpr int kN = 2048;
constexpr int kB = 16;
constexpr int kNB = 128;  // NUM_BUCKETS

// fl32(ln2) = 0x3F317218 — what any f32 log chain divides by (log(2.0f)).
#define LN2_BITS 0x3f317218u

// Native vector types (HIP's float4/int4 are classes; nontemporal builtin
// needs a true vector type).
typedef float f32x4 __attribute__((ext_vector_type(4)));
typedef int   i32x4 __attribute__((ext_vector_type(4)));

// ---------------------------------------------------------------------------
// Bucket matching the all-f32 arbiter chain with correctly-rounded f32 log
// (verified absmax 0.0 in R3 — DO NOT TOUCH):
//   bk = clip( floorf( fl32( CRlog32(a) / fl32(ln2) ) ), 0, 128 ), a = max(|dt|,1)
// Fast path 31-clz(a) is provably identical outside narrow windows around 2^j;
// inside, emulate with (float)log((double)a) + IEEE f32 divide.
// ---------------------------------------------------------------------------
__device__ __forceinline__ int bucket_of(int rowts, int tj) {
    int dt = rowts - tj;
    unsigned a = (unsigned)(dt < 0 ? -dt : dt);
    a = a < 1u ? 1u : a;                   // a in [1, 10^7) < 2^24
    int k = 31 - __clz((int)a);            // exact floor(log2(a))
    unsigned p = 1u << k;
    unsigned Wlo = ((p >> 20) * (unsigned)k) + 8u;
    unsigned Whi = ((p >> 19) * (unsigned)(k + 1)) + 8u;
    bool danger = ((a - p) < Wlo) | (((p << 1) - a) < Whi);
    if (!danger) return k;
    float L = (float)log((double)a);       // correctly-rounded f32 log(a)
    float q = L / __uint_as_float(LN2_BITS);  // IEEE f32 divide (no fast-math)
    int bk = (int)floorf(q);
    return bk < 0 ? 0 : (bk > kNB ? kNB : bk);
}

// ---------------------------------------------------------------------------
// Fused kernel: one block per output row (uniform shape: 2048 floats = 2
// f32x4 stores per thread @ 256 threads).
//   blocks [0, B*N)        : ts-bias row (b,i) of out[N*N + ...]
//   blocks [B*N, B*N + N)  : pos-bias row i of out[0 ...]
// Output is write-once and bigger than L3 -> nontemporal stores.
// ---------------------------------------------------------------------------
__global__ __launch_bounds__(256) void bias_kernel(const int* __restrict__ ts,
                                                   const float* __restrict__ pos_w,
                                                   const float* __restrict__ ts_w,
                                                   float* __restrict__ out) {
    const int blk = blockIdx.x;

    if (blk < kB * kN) {
        // ---- bucketized timestamp bias row ----
        __shared__ float w[kNB + 1];
        if (threadIdx.x <= kNB) w[threadIdx.x] = ts_w[threadIdx.x];
        __syncthreads();

        const int b = blk >> 11;            // / kN
        const int i = blk & (kN - 1);
        const int* __restrict__ tsrow = ts + (size_t)b * kN;
        const int rowts = tsrow[min(i + 1, kN - 1)];

        const i32x4* __restrict__ ts4 = (const i32x4*)tsrow;
        f32x4* __restrict__ orow4 =
            (f32x4*)(out + (size_t)kN * kN + (size_t)blk * kN);

        #pragma unroll
        for (int kk = 0; kk < kN / (4 * 256); ++kk) {
            const int v = kk * 256 + threadIdx.x;
            const i32x4 t4 = ts4[v];
            f32x4 r;
            r.x = w[bucket_of(rowts, t4.x)];
            r.y = w[bucket_of(rowts, t4.y)];
            r.z = w[bucket_of(rowts, t4.z)];
            r.w = w[bucket_of(rowts, t4.w)];
            __builtin_nontemporal_store(r, &orow4[v]);
        }
    } else {
        // ---- relative position bias row: out[i][j] = pos_w[N-1-i + j] ----
        const int i = blk - kB * kN;
        const float* __restrict__ src = pos_w + (kN - 1 - i);  // L1/L2-resident
        f32x4* __restrict__ orow4 = (f32x4*)(out + (size_t)i * kN);
        #pragma unroll
        for (int kk = 0; kk < kN / (4 * 256); ++kk) {
            const int v = kk * 256 + threadIdx.x;
            f32x4 r;
            r.x = src[4 * v + 0];
            r.y = src[4 * v + 1];
            r.z = src[4 * v + 2];
            r.w = src[4 * v + 3];
            __builtin_nontemporal_store(r, &orow4[v]);
        }
    }
}

extern "C" void kernel_launch(void* const* d_in, const int* in_sizes, int n_in,
                              void* d_out, int out_size, void* d_ws, size_t ws_size,
                              hipStream_t stream) {
    const int*   all_ts = (const int*)d_in[0];    // (B, N) int32
    const float* pos_w  = (const float*)d_in[1];  // (2N-1,) f32
    const float* ts_w   = (const float*)d_in[2];  // (NB+1,) f32
    float* out = (float*)d_out;                   // [N*N] pos ++ [B*N*N] ts

    bias_kernel<<<kB * kN + kN, 256, 0, stream>>>(all_ts, pos_w, ts_w, out);
}